// Round 5
// baseline (37.248 us; speedup 1.0000x reference)
//
#include <hip/hip_runtime.h>
#include <math.h>

#define GHM_DELTA 0.1f
#define GHM_EPS   1e-12f
#define N_FIX     16384
#define NBLK      512         // i-tiles of 32
#define TI        32
#define NTHR      1024        // 16 waves/block

__device__ __forceinline__ float softplus_ref(float x) {
    return fmaxf(x, 0.0f) + log1pf(expf(-fabsf(x)));
}
__device__ __forceinline__ float sigmoid_ref(float x) {
    return 1.0f / (1.0f + expf(-x));
}

// Fused: 512 blocks x 1024 threads, 64KB LDS (2 blocks/CU -> 32 waves/CU).
// Block bx owns i-tile [bx*32, bx*32+32). Wave wid=(ig, js): all 64 lanes of a
// wave share the same 8 i's (in VGPRs) and split j-slice js (4096 j's) by lane
// with CONSECUTIVE float4 reads (conflict-free). Counts: 6-step shfl_xor
// butterfly (exact int) -> one LDS write per wave into the dead g buffer ->
// wave 0 computes losses + double2 block partial. No atomics, fixed order.
__global__ __launch_bounds__(1024, 8) void ghm_fused(
    const float* __restrict__ logits,
    const int*   __restrict__ targets,
    const float* __restrict__ pos_weight,
    double*      __restrict__ bpart)      // [NBLK*2]
{
    __shared__ float gj[N_FIX];           // 64 KB; reused as pc[] after death

    const int tid  = threadIdx.x;
    const int bx   = blockIdx.x;
    const int lane = tid & 63;
    const int wid  = tid >> 6;            // 0..15
    const int ig   = wid & 3;             // i-group: 8 i's
    const int js   = wid >> 2;            // j-slice: 4096 j's

    // Stage g[j] for ALL j: 1024 thr x 4 iters x float4.
    {
        const float4* l4 = reinterpret_cast<const float4*>(logits);
        const int4*   t4 = reinterpret_cast<const int4*>(targets);
        float4*       g4 = reinterpret_cast<float4*>(gj);
        #pragma unroll
        for (int k = tid; k < N_FIX / 4; k += NTHR) {
            float4 x = l4[k];
            int4   y = t4[k];
            float4 r;
            r.x = fabsf(sigmoid_ref(x.x) - (float)y.x);
            r.y = fabsf(sigmoid_ref(x.y) - (float)y.y);
            r.z = fabsf(sigmoid_ref(x.z) - (float)y.z);
            r.w = fabsf(sigmoid_ref(x.w) - (float)y.w);
            g4[k] = r;
        }
    }

    // This wave's 8 gi in registers (same for all 64 lanes).
    const int i0 = bx * TI + ig * 8;
    float gi[8];
    {
        const float4* lx = reinterpret_cast<const float4*>(logits + i0);
        const int4*   ty = reinterpret_cast<const int4*>(targets + i0);
        float4 x0 = lx[0], x1 = lx[1];
        int4   y0 = ty[0], y1 = ty[1];
        gi[0] = fabsf(sigmoid_ref(x0.x) - (float)y0.x);
        gi[1] = fabsf(sigmoid_ref(x0.y) - (float)y0.y);
        gi[2] = fabsf(sigmoid_ref(x0.z) - (float)y0.z);
        gi[3] = fabsf(sigmoid_ref(x0.w) - (float)y0.w);
        gi[4] = fabsf(sigmoid_ref(x1.x) - (float)y1.x);
        gi[5] = fabsf(sigmoid_ref(x1.y) - (float)y1.y);
        gi[6] = fabsf(sigmoid_ref(x1.z) - (float)y1.z);
        gi[7] = fabsf(sigmoid_ref(x1.w) - (float)y1.w);
    }
    __syncthreads();

    // Compare loop: 16 consecutive-by-lane float4 reads, 8 i reuse each.
    int c0 = 0, c1 = 0, c2 = 0, c3 = 0, c4 = 0, c5 = 0, c6 = 0, c7 = 0;
    const float4* base = reinterpret_cast<const float4*>(gj) + js * 1024 + lane;
    #pragma unroll 4
    for (int jj = 0; jj < 16; ++jj) {
        float4 v = base[(size_t)jj * 64];
        c0 += (fabsf(gi[0] - v.x) <= GHM_DELTA) + (fabsf(gi[0] - v.y) <= GHM_DELTA)
            + (fabsf(gi[0] - v.z) <= GHM_DELTA) + (fabsf(gi[0] - v.w) <= GHM_DELTA);
        c1 += (fabsf(gi[1] - v.x) <= GHM_DELTA) + (fabsf(gi[1] - v.y) <= GHM_DELTA)
            + (fabsf(gi[1] - v.z) <= GHM_DELTA) + (fabsf(gi[1] - v.w) <= GHM_DELTA);
        c2 += (fabsf(gi[2] - v.x) <= GHM_DELTA) + (fabsf(gi[2] - v.y) <= GHM_DELTA)
            + (fabsf(gi[2] - v.z) <= GHM_DELTA) + (fabsf(gi[2] - v.w) <= GHM_DELTA);
        c3 += (fabsf(gi[3] - v.x) <= GHM_DELTA) + (fabsf(gi[3] - v.y) <= GHM_DELTA)
            + (fabsf(gi[3] - v.z) <= GHM_DELTA) + (fabsf(gi[3] - v.w) <= GHM_DELTA);
        c4 += (fabsf(gi[4] - v.x) <= GHM_DELTA) + (fabsf(gi[4] - v.y) <= GHM_DELTA)
            + (fabsf(gi[4] - v.z) <= GHM_DELTA) + (fabsf(gi[4] - v.w) <= GHM_DELTA);
        c5 += (fabsf(gi[5] - v.x) <= GHM_DELTA) + (fabsf(gi[5] - v.y) <= GHM_DELTA)
            + (fabsf(gi[5] - v.z) <= GHM_DELTA) + (fabsf(gi[5] - v.w) <= GHM_DELTA);
        c6 += (fabsf(gi[6] - v.x) <= GHM_DELTA) + (fabsf(gi[6] - v.y) <= GHM_DELTA)
            + (fabsf(gi[6] - v.z) <= GHM_DELTA) + (fabsf(gi[6] - v.w) <= GHM_DELTA);
        c7 += (fabsf(gi[7] - v.x) <= GHM_DELTA) + (fabsf(gi[7] - v.y) <= GHM_DELTA)
            + (fabsf(gi[7] - v.z) <= GHM_DELTA) + (fabsf(gi[7] - v.w) <= GHM_DELTA);
    }

    // Wave butterfly reduce (exact integer): all lanes end with the wave sums.
    #pragma unroll
    for (int mask = 1; mask < 64; mask <<= 1) {
        c0 += __shfl_xor(c0, mask, 64);
        c1 += __shfl_xor(c1, mask, 64);
        c2 += __shfl_xor(c2, mask, 64);
        c3 += __shfl_xor(c3, mask, 64);
        c4 += __shfl_xor(c4, mask, 64);
        c5 += __shfl_xor(c5, mask, 64);
        c6 += __shfl_xor(c6, mask, 64);
        c7 += __shfl_xor(c7, mask, 64);
    }

    __syncthreads();                      // g[] is now dead
    int* pc = reinterpret_cast<int*>(gj); // pc[js][i_loc]: [4][32]
    if (lane == 0) {
        int* d = pc + js * TI + ig * 8;   // static indices only
        d[0] = c0; d[1] = c1; d[2] = c2; d[3] = c3;
        d[4] = c4; d[5] = c5; d[6] = c6; d[7] = c7;
    }
    __syncthreads();

    if (tid < 64) {
        double wd = 0.0, pd = 0.0;
        if (tid < TI) {
            int cnt = pc[tid] + pc[TI + tid] + pc[2 * TI + tid] + pc[3 * TI + tid];
            const int i = bx * TI + tid;
            float x  = logits[i];
            float y  = (float)targets[i];
            float GD   = (float)cnt / GHM_DELTA;
            float beta = (float)N_FIX / (GD + GHM_EPS);
            float pw   = pos_weight[0];
            float per  = pw * y * softplus_ref(-x) + (1.0f - y) * softplus_ref(x);
            wd = (double)(beta * per);
            pd = (double)per;
        }
        #pragma unroll
        for (int off = 32; off >= 1; off >>= 1) {
            wd += __shfl_down(wd, off, 64);
            pd += __shfl_down(pd, off, 64);
        }
        if (tid == 0) {
            bpart[bx * 2]     = wd;
            bpart[bx * 2 + 1] = pd;
        }
    }
}

// Final reduce of 512 block partials (fixed order -> deterministic).
__global__ __launch_bounds__(512) void ghm_reduce(
    const double* __restrict__ bpart, float* __restrict__ out, int n)
{
    __shared__ double red[16];
    const int t = threadIdx.x;
    double wd = bpart[2 * t];
    double pd = bpart[2 * t + 1];
    #pragma unroll
    for (int off = 32; off >= 1; off >>= 1) {
        wd += __shfl_down(wd, off, 64);
        pd += __shfl_down(pd, off, 64);
    }
    const int wave = t >> 6;
    if ((t & 63) == 0) { red[wave * 2] = wd; red[wave * 2 + 1] = pd; }
    __syncthreads();
    if (t == 0) {
        double sw = 0.0, sp = 0.0;
        #pragma unroll
        for (int k = 0; k < 8; ++k) { sw += red[2 * k]; sp += red[2 * k + 1]; }
        out[0] = (float)(sw / (double)n);
        out[1] = (float)(sp / (double)n);
    }
}

extern "C" void kernel_launch(void* const* d_in, const int* in_sizes, int n_in,
                              void* d_out, int out_size, void* d_ws, size_t ws_size,
                              hipStream_t stream) {
    const float* logits     = (const float*)d_in[0];
    const int*   targets    = (const int*)d_in[1];
    const float* pos_weight = (const float*)d_in[2];
    float* out = (float*)d_out;
    const int n = in_sizes[0];            // 16384

    double* bpart = (double*)d_ws;        // NBLK*2 doubles

    ghm_fused<<<NBLK, NTHR, 0, stream>>>(logits, targets, pos_weight, bpart);
    ghm_reduce<<<1, NBLK, 0, stream>>>(bpart, out, n);
}